// Round 6
// baseline (386.984 us; speedup 1.0000x reference)
//
#include <hip/hip_runtime.h>

#define DIM 64
#define NG  16          // num graphs (fixed by problem setup)
#define CPG 8           // edge chunks per graph
#define NPG 4096        // nodes per graph (fixed)
#define LSTR 68

// ---------------------------------------------------------------------------
// B1: per-chunk LDS sub-histograms (NG*CPG blocks). No global atomics.
// ---------------------------------------------------------------------------
__global__ __launch_bounds__(256) void b1_hist(
    const int* __restrict__ src, const int* __restrict__ dst,
    int* __restrict__ hsub, int* __restrict__ dsub, int chunk, int npg)
{
    __shared__ int hs[NPG], hd[NPG];
    const int blk = blockIdx.x;
    const int g = blk / CPG;
    const int t = threadIdx.x;
    const int ebase = blk * chunk;     // chunks are graph-major contiguous
    const int nbase = g * npg;
    for (int i = t; i < npg; i += 256) { hs[i] = 0; hd[i] = 0; }
    __syncthreads();
    for (int e = t; e < chunk; e += 256) {
        atomicAdd(&hs[src[ebase + e] - nbase], 1);
        atomicAdd(&hd[dst[ebase + e] - nbase], 1);
    }
    __syncthreads();
    for (int i = t; i < npg; i += 256) {
        hsub[blk * npg + i] = hs[i];
        dsub[blk * npg + i] = hd[i];
    }
}

// ---------------------------------------------------------------------------
// B2: one block per graph. Sum sub-hists -> norms; in-block exclusive scan of
// dst degrees -> rowptr; in-place prefix over chunks -> per-chunk absolute
// cursor starts (stable counting sort).
// ---------------------------------------------------------------------------
__global__ __launch_bounds__(1024) void b2_scan(
    const int* __restrict__ hsub, int* __restrict__ dsub,
    float* __restrict__ ns, float* __restrict__ nd,
    int* __restrict__ rowptr, int epg, int npg, int N, int E)
{
    __shared__ int tsum[1024];
    const int g = blockIdx.x;
    const int t = threadIdx.x;
    const int nbase = g * npg;
    const int ebase = g * epg;
    const int i0 = t * 4;

    int dtot[4];
#pragma unroll
    for (int r = 0; r < 4; ++r) {
        int i = i0 + r;
        int sd = 0, dd = 0;
        for (int k = 0; k < CPG; ++k) {
            sd += hsub[(g * CPG + k) * npg + i];
            dd += dsub[(g * CPG + k) * npg + i];
        }
        dtot[r] = dd;
        ns[nbase + i] = sd > 0 ? rsqrtf((float)sd) : 0.0f;
        nd[nbase + i] = dd > 0 ? rsqrtf((float)dd) : 0.0f;
    }
    int s4 = dtot[0] + dtot[1] + dtot[2] + dtot[3];
    tsum[t] = s4;
    __syncthreads();
    for (int off = 1; off < 1024; off <<= 1) {
        int x = (t >= off) ? tsum[t - off] : 0;
        __syncthreads();
        tsum[t] += x;
        __syncthreads();
    }
    int c = ebase + (tsum[t] - s4);
#pragma unroll
    for (int r = 0; r < 4; ++r) {
        int i = i0 + r;
        rowptr[nbase + i] = c;
        int cc = c;
        for (int k = 0; k < CPG; ++k) {
            int* p = &dsub[(g * CPG + k) * npg + i];
            int old = *p; *p = cc; cc += old;
        }
        c += dtot[r];
    }
    if (g == 0 && t == 0) rowptr[N] = E;
}

// ---------------------------------------------------------------------------
// B3: fill ssrc. LDS cursors init from per-chunk starts. No global atomics.
// ---------------------------------------------------------------------------
__global__ __launch_bounds__(256) void b3_fill(
    const int* __restrict__ src, const int* __restrict__ dst,
    const int* __restrict__ dsub, int* __restrict__ ssrc, int chunk, int npg)
{
    __shared__ int cur[NPG];
    const int blk = blockIdx.x;
    const int g = blk / CPG;
    const int t = threadIdx.x;
    const int ebase = blk * chunk;
    const int nbase = g * npg;
    for (int i = t; i < npg; i += 256) cur[i] = dsub[blk * npg + i];
    __syncthreads();
    for (int e = t; e < chunk; e += 256) {
        int s = src[ebase + e];
        int d = dst[ebase + e] - nbase;
        int pos = atomicAdd(&cur[d], 1);
        ssrc[pos] = s;
    }
}

// ---------------------------------------------------------------------------
// Fused layer: per dst node i (one wave each):
//   acc = sum_{s in in-edges} [edge_ns ? ns[s]* : ] in[s,:]      (gather)
//   res = acc @ W                                                 (matvec)
//   out[i,:] = [ep_ns ? ns[i]* : ] (nd[i]*res + bias)             (epilogue)
// Uses A(ns.X)W == (A(ns.X))W re-association; layers 2/3 read inputs already
// prescaled by ns (folded into the previous layer's epilogue via ep_ns).
// 1024-thread blocks (16 nodes) amortize the 16KB W stage; matvec broadcasts
// the aggregated row via __shfl (readlane) against LDS-transposed W.
// ---------------------------------------------------------------------------
__global__ __launch_bounds__(1024) void fused_layer(
    const float* __restrict__ in, const float* __restrict__ W,
    const float* __restrict__ bias,
    const float* __restrict__ ns, const float* __restrict__ nd,
    const int* __restrict__ ssrc, const int* __restrict__ rowptr,
    float* __restrict__ out, int N, int edge_ns, int ep_ns, int swiz)
{
    __shared__ float Wt[64 * LSTR];    // Wt[c][k] = W[k][c]
    const int tid = threadIdx.x;
    int blk = blockIdx.x;
    if (swiz) {                        // 4096 blocks: 16 graphs x 256
        int x = blk & 7;               // XCD (dispatch round-robin heuristic)
        int j = blk >> 3;
        int g = x + ((j >> 8) << 3);
        blk = (g << 8) + (j & 255);
    }

    for (int i = tid; i < 64 * 64; i += 1024) {
        int k = i >> 6, c = i & 63;
        Wt[c * LSTR + k] = W[i];
    }
    __syncthreads();

    const int wave = tid >> 6;
    const int lane = tid & 63;
    const int wid = blk * 16 + wave;

    float4 acc = {0.f, 0.f, 0.f, 0.f};
    if (wid < N) {
        int beg = rowptr[wid], end = rowptr[wid + 1];
        int grp = lane >> 4;
        int sub = lane & 15;
        int j = beg + grp;
        if (edge_ns) {
            for (; j + 4 < end; j += 8) {
                int s0 = ssrc[j], s1 = ssrc[j + 4];
                float n0 = ns[s0], n1 = ns[s1];
                const float4 v0 = *(const float4*)(in + (size_t)s0 * 64 + sub * 4);
                const float4 v1 = *(const float4*)(in + (size_t)s1 * 64 + sub * 4);
                acc.x += n0 * v0.x + n1 * v1.x;
                acc.y += n0 * v0.y + n1 * v1.y;
                acc.z += n0 * v0.z + n1 * v1.z;
                acc.w += n0 * v0.w + n1 * v1.w;
            }
            if (j < end) {
                int s = ssrc[j];
                float n = ns[s];
                const float4 v = *(const float4*)(in + (size_t)s * 64 + sub * 4);
                acc.x += n * v.x; acc.y += n * v.y;
                acc.z += n * v.z; acc.w += n * v.w;
            }
        } else {
            for (; j + 4 < end; j += 8) {
                int s0 = ssrc[j], s1 = ssrc[j + 4];
                const float4 v0 = *(const float4*)(in + (size_t)s0 * 64 + sub * 4);
                const float4 v1 = *(const float4*)(in + (size_t)s1 * 64 + sub * 4);
                acc.x += v0.x + v1.x; acc.y += v0.y + v1.y;
                acc.z += v0.z + v1.z; acc.w += v0.w + v1.w;
            }
            if (j < end) {
                int s = ssrc[j];
                const float4 v = *(const float4*)(in + (size_t)s * 64 + sub * 4);
                acc.x += v.x; acc.y += v.y; acc.z += v.z; acc.w += v.w;
            }
        }
    }
    // reduce 4 edge-groups -> lanes 0..15 hold the 64 aggregated features
#pragma unroll
    for (int off = 32; off >= 16; off >>= 1) {
        acc.x += __shfl_down(acc.x, off, 64);
        acc.y += __shfl_down(acc.y, off, 64);
        acc.z += __shfl_down(acc.z, off, 64);
        acc.w += __shfl_down(acc.w, off, 64);
    }
    // matvec: res[lane] = sum_k acc[k] * W[k][lane]; acc[k] broadcast via shfl
    float res = 0.f;
#pragma unroll
    for (int k4 = 0; k4 < 16; ++k4) {
        const float4 w = *(const float4*)&Wt[lane * LSTR + 4 * k4];
        res += __shfl(acc.x, k4, 64) * w.x + __shfl(acc.y, k4, 64) * w.y
             + __shfl(acc.z, k4, 64) * w.z + __shfl(acc.w, k4, 64) * w.w;
    }
    if (wid < N) {
        float r = nd[wid] * res + bias[lane];
        if (ep_ns) r *= ns[wid];
        out[(size_t)wid * 64 + lane] = r;
    }
}

// ---------------------------------------------------------------------------
extern "C" void kernel_launch(void* const* d_in, const int* in_sizes, int n_in,
                              void* d_out, int out_size, void* d_ws, size_t ws_size,
                              hipStream_t stream)
{
    const float* x  = (const float*)d_in[0];
    const float* W1 = (const float*)d_in[1];
    const float* b1 = (const float*)d_in[2];
    const float* W2 = (const float*)d_in[3];
    const float* b2 = (const float*)d_in[4];
    const float* W3 = (const float*)d_in[5];
    const float* b3 = (const float*)d_in[6];
    const int*  src = (const int*)d_in[7];
    const int*  dst = (const int*)d_in[8];

    const int E = in_sizes[7];
    const int N = in_sizes[0] / DIM;
    const int epg = E / NG;
    const int npg = N / NG;
    const int chunk = epg / CPG;

    // ws layout: ns[N] | nd[N] | hA[N*64] | hB[N*64] | rowptr[N+1] | ssrc[E]
    // hsub/dsub (2MB each) alias hA: consumed before layer 1 writes hA.
    float* ns     = (float*)d_ws;
    float* nd     = ns + N;
    float* hA     = nd + N;
    float* hB     = hA + (size_t)N * DIM;
    int*   rowptr = (int*)(hB + (size_t)N * DIM);
    int*   ssrc   = rowptr + N + 1;
    int*   hsub   = (int*)hA;
    int*   dsub   = hsub + (size_t)NG * CPG * npg;
    float* outp   = (float*)d_out;

    b1_hist<<<NG * CPG, 256, 0, stream>>>(src, dst, hsub, dsub, chunk, npg);
    b2_scan<<<NG, 1024, 0, stream>>>(hsub, dsub, ns, nd, rowptr, epg, npg, N, E);
    b3_fill<<<NG * CPG, 256, 0, stream>>>(src, dst, dsub, ssrc, chunk, npg);

    const int blocks = (N + 15) / 16;
    const int swiz = (N == 65536 && npg == 4096) ? 1 : 0;

    // L1: gather ns-scaled x; epilogue folds next layer's ns prescale
    fused_layer<<<blocks, 1024, 0, stream>>>(x,  W1, b1, ns, nd, ssrc, rowptr, hA,   N, 1, 1, swiz);
    // L2: inputs prescaled; epilogue folds ns again
    fused_layer<<<blocks, 1024, 0, stream>>>(hA, W2, b2, ns, nd, ssrc, rowptr, hB,   N, 0, 1, swiz);
    // L3: final — plain epilogue to d_out
    fused_layer<<<blocks, 1024, 0, stream>>>(hB, W3, b3, ns, nd, ssrc, rowptr, outp, N, 0, 0, swiz);
}

// Round 7
// 277.201 us; speedup vs baseline: 1.3960x; 1.3960x over previous
//
#include <hip/hip_runtime.h>

#define DIM 64
#define NG  16          // num graphs (fixed by problem setup)
#define CPG 8           // edge chunks per graph
#define NPG 4096        // nodes per graph (fixed)

// ---------------------------------------------------------------------------
// B1: per-chunk LDS sub-histograms (NG*CPG blocks). No global atomics.
// ---------------------------------------------------------------------------
__global__ __launch_bounds__(256) void b1_hist(
    const int* __restrict__ src, const int* __restrict__ dst,
    int* __restrict__ hsub, int* __restrict__ dsub, int chunk, int npg)
{
    __shared__ int hs[NPG], hd[NPG];
    const int blk = blockIdx.x;
    const int g = blk / CPG;
    const int t = threadIdx.x;
    const int ebase = blk * chunk;     // chunks are graph-major contiguous
    const int nbase = g * npg;
    for (int i = t; i < npg; i += 256) { hs[i] = 0; hd[i] = 0; }
    __syncthreads();
    for (int e = t; e < chunk; e += 256) {
        atomicAdd(&hs[src[ebase + e] - nbase], 1);
        atomicAdd(&hd[dst[ebase + e] - nbase], 1);
    }
    __syncthreads();
    for (int i = t; i < npg; i += 256) {
        hsub[blk * npg + i] = hs[i];
        dsub[blk * npg + i] = hd[i];
    }
}

// ---------------------------------------------------------------------------
// B2: one block per graph. Sum sub-hists -> norms; in-block exclusive scan of
// dst degrees -> rowptr; in-place prefix over chunks -> per-chunk absolute
// cursor starts (stable counting sort).
// ---------------------------------------------------------------------------
__global__ __launch_bounds__(1024) void b2_scan(
    const int* __restrict__ hsub, int* __restrict__ dsub,
    float* __restrict__ ns, float* __restrict__ nd,
    int* __restrict__ rowptr, int epg, int npg, int N, int E)
{
    __shared__ int tsum[1024];
    const int g = blockIdx.x;
    const int t = threadIdx.x;
    const int nbase = g * npg;
    const int ebase = g * epg;
    const int i0 = t * 4;

    int dtot[4];
#pragma unroll
    for (int r = 0; r < 4; ++r) {
        int i = i0 + r;
        int sd = 0, dd = 0;
        for (int k = 0; k < CPG; ++k) {
            sd += hsub[(g * CPG + k) * npg + i];
            dd += dsub[(g * CPG + k) * npg + i];
        }
        dtot[r] = dd;
        ns[nbase + i] = sd > 0 ? rsqrtf((float)sd) : 0.0f;
        nd[nbase + i] = dd > 0 ? rsqrtf((float)dd) : 0.0f;
    }
    int s4 = dtot[0] + dtot[1] + dtot[2] + dtot[3];
    tsum[t] = s4;
    __syncthreads();
    for (int off = 1; off < 1024; off <<= 1) {
        int x = (t >= off) ? tsum[t - off] : 0;
        __syncthreads();
        tsum[t] += x;
        __syncthreads();
    }
    int c = ebase + (tsum[t] - s4);
#pragma unroll
    for (int r = 0; r < 4; ++r) {
        int i = i0 + r;
        rowptr[nbase + i] = c;
        int cc = c;
        for (int k = 0; k < CPG; ++k) {
            int* p = &dsub[(g * CPG + k) * npg + i];
            int old = *p; *p = cc; cc += old;
        }
        c += dtot[r];
    }
    if (g == 0 && t == 0) rowptr[N] = E;
}

// ---------------------------------------------------------------------------
// B3: fill ssrc. LDS cursors init from per-chunk starts. No global atomics.
// ---------------------------------------------------------------------------
__global__ __launch_bounds__(256) void b3_fill(
    const int* __restrict__ src, const int* __restrict__ dst,
    const int* __restrict__ dsub, int* __restrict__ ssrc, int chunk, int npg)
{
    __shared__ int cur[NPG];
    const int blk = blockIdx.x;
    const int g = blk / CPG;
    const int t = threadIdx.x;
    const int ebase = blk * chunk;
    const int nbase = g * npg;
    for (int i = t; i < npg; i += 256) cur[i] = dsub[blk * npg + i];
    __syncthreads();
    for (int e = t; e < chunk; e += 256) {
        int s = src[ebase + e];
        int d = dst[ebase + e] - nbase;
        int pos = atomicAdd(&cur[d], 1);
        ssrc[pos] = s;
    }
}

// ---------------------------------------------------------------------------
// GEMM: out[row,:] = (in[row,:]*alpha + beta*bprev) @ W
//   has_prev=0: alpha=ns[row]               (layer 1)
//   has_prev=1: alpha=ns[row]*nd[row], beta=ns[row]  (folds prev epilogue)
// swiz=1: XCD-affine remap (graph g -> XCD g%8, matching gather).
// ---------------------------------------------------------------------------
#define LSTR 68
__global__ __launch_bounds__(256) void gemm_kernel(
    const float* __restrict__ in, const float* __restrict__ W,
    const float* __restrict__ bprev,
    const float* __restrict__ ns, const float* __restrict__ nd,
    float* __restrict__ out, int has_prev, int swiz)
{
    __shared__ float Wt[64 * LSTR];   // Wt[c][k]
    __shared__ float xs[32 * LSTR];   // xs[r][k]
    const int tid = threadIdx.x;
    int blk = blockIdx.x;
    if (swiz) {                        // 2048 blocks: 16 graphs x 128
        int x = blk & 7;
        int j = blk >> 3;
        int g = x + ((j >> 7) << 3);
        blk = (g << 7) + (j & 127);
    }
    const int row0 = blk * 32;

    for (int i = tid; i < 64 * 64; i += 256) {
        int k = i >> 6, c = i & 63;
        Wt[c * LSTR + k] = W[i];
    }
    for (int i = tid; i < 32 * 64; i += 256) {
        int r = i >> 6, c = i & 63;
        int row = row0 + r;
        float s = ns[row];
        float a = has_prev ? s * nd[row] : s;
        float bc = has_prev ? s : 0.0f;
        xs[r * LSTR + c] = in[row * 64 + c] * a + bc * bprev[c];
    }
    __syncthreads();

    const int c0 = tid & 31;
    const int r0 = tid >> 5;
    float acc[4][2] = {};
#pragma unroll
    for (int k = 0; k < 64; k += 4) {
        float4 w0 = *(const float4*)&Wt[(c0     ) * LSTR + k];
        float4 w1 = *(const float4*)&Wt[(c0 + 32) * LSTR + k];
#pragma unroll
        for (int rr = 0; rr < 4; ++rr) {
            float4 xv = *(const float4*)&xs[(r0 + 8 * rr) * LSTR + k];
            acc[rr][0] += xv.x * w0.x + xv.y * w0.y + xv.z * w0.z + xv.w * w0.w;
            acc[rr][1] += xv.x * w1.x + xv.y * w1.y + xv.z * w1.z + xv.w * w1.w;
        }
    }
#pragma unroll
    for (int rr = 0; rr < 4; ++rr) {
        int row = row0 + r0 + 8 * rr;
        out[row * 64 + c0     ] = acc[rr][0];
        out[row * 64 + c0 + 32] = acc[rr][1];
    }
}

// ---------------------------------------------------------------------------
// Gather: one wave per dst node; 4 edge-groups of 16 lanes x float4,
// ILP x4 -> 16 edges in flight per wave (one full avg-degree row per
// latency round). XCD swizzle keeps each graph's h slice L2-local.
// fuse_ep=1: out = acc*nd[node] + b (final epilogue fused).
// ---------------------------------------------------------------------------
__global__ __launch_bounds__(256) void gather_kernel(
    const float* __restrict__ h, const int* __restrict__ ssrc,
    const int* __restrict__ rowptr, float* __restrict__ out,
    const float* __restrict__ nd, const float* __restrict__ b,
    int N, int fuse_ep, int swiz)
{
    int blk = blockIdx.x;
    if (swiz) {                        // 16384 blocks: 16 graphs x 1024
        int x = blk & 7;
        int j = blk >> 3;
        int g = x + ((j >> 10) << 3);
        blk = (g << 10) + (j & 1023);
    }
    int wid  = blk * 4 + (threadIdx.x >> 6);
    int lane = threadIdx.x & 63;
    if (wid >= N) return;
    int beg = rowptr[wid], end = rowptr[wid + 1];
    int grp = lane >> 4;
    int sub = lane & 15;
    float4 acc = {0.f, 0.f, 0.f, 0.f};
    int j = beg + grp;
    for (; j + 12 < end; j += 16) {     // 4 independent chains per group
        int s0 = ssrc[j];
        int s1 = ssrc[j + 4];
        int s2 = ssrc[j + 8];
        int s3 = ssrc[j + 12];
        const float4 v0 = *(const float4*)(h + (size_t)s0 * 64 + sub * 4);
        const float4 v1 = *(const float4*)(h + (size_t)s1 * 64 + sub * 4);
        const float4 v2 = *(const float4*)(h + (size_t)s2 * 64 + sub * 4);
        const float4 v3 = *(const float4*)(h + (size_t)s3 * 64 + sub * 4);
        acc.x += (v0.x + v1.x) + (v2.x + v3.x);
        acc.y += (v0.y + v1.y) + (v2.y + v3.y);
        acc.z += (v0.z + v1.z) + (v2.z + v3.z);
        acc.w += (v0.w + v1.w) + (v2.w + v3.w);
    }
    for (; j < end; j += 4) {
        int s = ssrc[j];
        const float4 v = *(const float4*)(h + (size_t)s * 64 + sub * 4);
        acc.x += v.x; acc.y += v.y; acc.z += v.z; acc.w += v.w;
    }
#pragma unroll
    for (int off = 32; off >= 16; off >>= 1) {
        acc.x += __shfl_down(acc.x, off, 64);
        acc.y += __shfl_down(acc.y, off, 64);
        acc.z += __shfl_down(acc.z, off, 64);
        acc.w += __shfl_down(acc.w, off, 64);
    }
    if (lane < 16) {
        if (fuse_ep) {
            float n = nd[wid];
            const float4 bv = *(const float4*)(b + lane * 4);
            acc.x = acc.x * n + bv.x;
            acc.y = acc.y * n + bv.y;
            acc.z = acc.z * n + bv.z;
            acc.w = acc.w * n + bv.w;
        }
        *(float4*)(out + (size_t)wid * 64 + lane * 4) = acc;
    }
}

// ---------------------------------------------------------------------------
extern "C" void kernel_launch(void* const* d_in, const int* in_sizes, int n_in,
                              void* d_out, int out_size, void* d_ws, size_t ws_size,
                              hipStream_t stream)
{
    const float* x  = (const float*)d_in[0];
    const float* W1 = (const float*)d_in[1];
    const float* b1 = (const float*)d_in[2];
    const float* W2 = (const float*)d_in[3];
    const float* b2 = (const float*)d_in[4];
    const float* W3 = (const float*)d_in[5];
    const float* b3 = (const float*)d_in[6];
    const int*  src = (const int*)d_in[7];
    const int*  dst = (const int*)d_in[8];

    const int E = in_sizes[7];
    const int N = in_sizes[0] / DIM;
    const int epg = E / NG;
    const int npg = N / NG;
    const int chunk = epg / CPG;

    // ws layout: ns[N] | nd[N] | h[N*64] | rowptr[N+1] | ssrc[E]
    // hsub/dsub (2 MB each) alias h: consumed before gemm1 writes h.
    float* ns     = (float*)d_ws;
    float* nd     = ns + N;
    float* h      = nd + N;
    int*   rowptr = (int*)(h + (size_t)N * DIM);
    int*   ssrc   = rowptr + N + 1;
    int*   hsub   = (int*)h;
    int*   dsub   = hsub + (size_t)NG * CPG * npg;
    float* agg    = (float*)d_out;

    b1_hist<<<NG * CPG, 256, 0, stream>>>(src, dst, hsub, dsub, chunk, npg);
    b2_scan<<<NG, 1024, 0, stream>>>(hsub, dsub, ns, nd, rowptr, epg, npg, N, E);
    b3_fill<<<NG * CPG, 256, 0, stream>>>(src, dst, dsub, ssrc, chunk, npg);

    const int gemm_blocks = N / 32;
    const int agg_blocks  = N / 4;
    const int swiz = (N == 65536 && npg == 4096) ? 1 : 0;

    gemm_kernel<<<gemm_blocks, 256, 0, stream>>>(x, W1, b1, ns, nd, h, 0, swiz);
    gather_kernel<<<agg_blocks, 256, 0, stream>>>(h, ssrc, rowptr, agg, nd, b3, N, 0, swiz);

    gemm_kernel<<<gemm_blocks, 256, 0, stream>>>(agg, W2, b1, ns, nd, h, 1, swiz);
    gather_kernel<<<agg_blocks, 256, 0, stream>>>(h, ssrc, rowptr, agg, nd, b3, N, 0, swiz);

    gemm_kernel<<<gemm_blocks, 256, 0, stream>>>(agg, W3, b2, ns, nd, h, 1, swiz);
    gather_kernel<<<agg_blocks, 256, 0, stream>>>(h, ssrc, rowptr, agg, nd, b3, N, 1, swiz);
}

// Round 8
// 259.745 us; speedup vs baseline: 1.4899x; 1.0672x over previous
//
#include <hip/hip_runtime.h>
#include <hip/hip_fp16.h>

#define DIM 64
#define NG  16          // num graphs (fixed by problem setup)
#define CPG 8           // edge chunks per graph
#define NPG 4096        // nodes per graph (fixed)

// ---------------------------------------------------------------------------
// B1: per-chunk LDS sub-histograms (NG*CPG blocks). No global atomics.
// ---------------------------------------------------------------------------
__global__ __launch_bounds__(256) void b1_hist(
    const int* __restrict__ src, const int* __restrict__ dst,
    int* __restrict__ hsub, int* __restrict__ dsub, int chunk, int npg)
{
    __shared__ int hs[NPG], hd[NPG];
    const int blk = blockIdx.x;
    const int g = blk / CPG;
    const int t = threadIdx.x;
    const int ebase = blk * chunk;     // chunks are graph-major contiguous
    const int nbase = g * npg;
    for (int i = t; i < npg; i += 256) { hs[i] = 0; hd[i] = 0; }
    __syncthreads();
    for (int e = t; e < chunk; e += 256) {
        atomicAdd(&hs[src[ebase + e] - nbase], 1);
        atomicAdd(&hd[dst[ebase + e] - nbase], 1);
    }
    __syncthreads();
    for (int i = t; i < npg; i += 256) {
        hsub[blk * npg + i] = hs[i];
        dsub[blk * npg + i] = hd[i];
    }
}

// ---------------------------------------------------------------------------
// B2: one block per graph. Sum sub-hists -> norms; in-block exclusive scan of
// dst degrees -> rowptr; in-place prefix over chunks -> per-chunk absolute
// cursor starts (stable counting sort).
// ---------------------------------------------------------------------------
__global__ __launch_bounds__(1024) void b2_scan(
    const int* __restrict__ hsub, int* __restrict__ dsub,
    float* __restrict__ ns, float* __restrict__ nd,
    int* __restrict__ rowptr, int epg, int npg, int N, int E)
{
    __shared__ int tsum[1024];
    const int g = blockIdx.x;
    const int t = threadIdx.x;
    const int nbase = g * npg;
    const int ebase = g * epg;
    const int i0 = t * 4;

    int dtot[4];
#pragma unroll
    for (int r = 0; r < 4; ++r) {
        int i = i0 + r;
        int sd = 0, dd = 0;
        for (int k = 0; k < CPG; ++k) {
            sd += hsub[(g * CPG + k) * npg + i];
            dd += dsub[(g * CPG + k) * npg + i];
        }
        dtot[r] = dd;
        ns[nbase + i] = sd > 0 ? rsqrtf((float)sd) : 0.0f;
        nd[nbase + i] = dd > 0 ? rsqrtf((float)dd) : 0.0f;
    }
    int s4 = dtot[0] + dtot[1] + dtot[2] + dtot[3];
    tsum[t] = s4;
    __syncthreads();
    for (int off = 1; off < 1024; off <<= 1) {
        int x = (t >= off) ? tsum[t - off] : 0;
        __syncthreads();
        tsum[t] += x;
        __syncthreads();
    }
    int c = ebase + (tsum[t] - s4);
#pragma unroll
    for (int r = 0; r < 4; ++r) {
        int i = i0 + r;
        rowptr[nbase + i] = c;
        int cc = c;
        for (int k = 0; k < CPG; ++k) {
            int* p = &dsub[(g * CPG + k) * npg + i];
            int old = *p; *p = cc; cc += old;
        }
        c += dtot[r];
    }
    if (g == 0 && t == 0) rowptr[N] = E;
}

// ---------------------------------------------------------------------------
// B3: fill ssrc. LDS cursors init from per-chunk starts. No global atomics.
// ---------------------------------------------------------------------------
__global__ __launch_bounds__(256) void b3_fill(
    const int* __restrict__ src, const int* __restrict__ dst,
    const int* __restrict__ dsub, int* __restrict__ ssrc, int chunk, int npg)
{
    __shared__ int cur[NPG];
    const int blk = blockIdx.x;
    const int g = blk / CPG;
    const int t = threadIdx.x;
    const int ebase = blk * chunk;
    const int nbase = g * npg;
    for (int i = t; i < npg; i += 256) cur[i] = dsub[blk * npg + i];
    __syncthreads();
    for (int e = t; e < chunk; e += 256) {
        int s = src[ebase + e];
        int d = dst[ebase + e] - nbase;
        int pos = atomicAdd(&cur[d], 1);
        ssrc[pos] = s;
    }
}

// ---------------------------------------------------------------------------
// GEMM: out[row,:] = fp16( (in[row,:]*alpha + beta*bprev) @ W )
//   has_prev=0: alpha=ns[row]               (layer 1)
//   has_prev=1: alpha=ns[row]*nd[row], beta=ns[row]  (folds prev epilogue)
// Output stored as fp16 (gather is the only consumer; halves gather bytes).
// swiz=1: XCD-affine remap (graph g -> XCD g%8, matching gather).
// ---------------------------------------------------------------------------
#define LSTR 68
__global__ __launch_bounds__(256) void gemm_kernel(
    const float* __restrict__ in, const float* __restrict__ W,
    const float* __restrict__ bprev,
    const float* __restrict__ ns, const float* __restrict__ nd,
    __half* __restrict__ out, int has_prev, int swiz)
{
    __shared__ float Wt[64 * LSTR];   // Wt[c][k]
    __shared__ float xs[32 * LSTR];   // xs[r][k]
    const int tid = threadIdx.x;
    int blk = blockIdx.x;
    if (swiz) {                        // 2048 blocks: 16 graphs x 128
        int x = blk & 7;
        int j = blk >> 3;
        int g = x + ((j >> 7) << 3);
        blk = (g << 7) + (j & 127);
    }
    const int row0 = blk * 32;

    for (int i = tid; i < 64 * 64; i += 256) {
        int k = i >> 6, c = i & 63;
        Wt[c * LSTR + k] = W[i];
    }
    for (int i = tid; i < 32 * 64; i += 256) {
        int r = i >> 6, c = i & 63;
        int row = row0 + r;
        float s = ns[row];
        float a = has_prev ? s * nd[row] : s;
        float bc = has_prev ? s : 0.0f;
        xs[r * LSTR + c] = in[row * 64 + c] * a + bc * bprev[c];
    }
    __syncthreads();

    const int c0 = tid & 31;
    const int r0 = tid >> 5;
    float acc[4][2] = {};
#pragma unroll
    for (int k = 0; k < 64; k += 4) {
        float4 w0 = *(const float4*)&Wt[(c0     ) * LSTR + k];
        float4 w1 = *(const float4*)&Wt[(c0 + 32) * LSTR + k];
#pragma unroll
        for (int rr = 0; rr < 4; ++rr) {
            float4 xv = *(const float4*)&xs[(r0 + 8 * rr) * LSTR + k];
            acc[rr][0] += xv.x * w0.x + xv.y * w0.y + xv.z * w0.z + xv.w * w0.w;
            acc[rr][1] += xv.x * w1.x + xv.y * w1.y + xv.z * w1.z + xv.w * w1.w;
        }
    }
#pragma unroll
    for (int rr = 0; rr < 4; ++rr) {
        int row = row0 + r0 + 8 * rr;
        out[row * 64 + c0     ] = __float2half_rn(acc[rr][0]);
        out[row * 64 + c0 + 32] = __float2half_rn(acc[rr][1]);
    }
}

// ---------------------------------------------------------------------------
// Gather (fp16 source): one wave per dst node; 4 edge-groups of 16 lanes x
// 8B (4 halves), ILP x4 -> 16 edges in flight. Row = 128B -> 1-2 L2 requests
// per edge (vs 4 at fp32). Accumulate fp32. XCD swizzle for L2 locality.
// fuse_ep=1: out = acc*nd[node] + b (final epilogue fused).
// ---------------------------------------------------------------------------
__device__ __forceinline__ void acc_h4(float4& acc, uint2 u)
{
    __half2 p = *(__half2*)&u.x;
    __half2 q = *(__half2*)&u.y;
    float2 f0 = __half22float2(p);
    float2 f1 = __half22float2(q);
    acc.x += f0.x; acc.y += f0.y; acc.z += f1.x; acc.w += f1.y;
}

__global__ __launch_bounds__(256) void gather_kernel(
    const __half* __restrict__ h, const int* __restrict__ ssrc,
    const int* __restrict__ rowptr, float* __restrict__ out,
    const float* __restrict__ nd, const float* __restrict__ b,
    int N, int fuse_ep, int swiz)
{
    int blk = blockIdx.x;
    if (swiz) {                        // 16384 blocks: 16 graphs x 1024
        int x = blk & 7;
        int j = blk >> 3;
        int g = x + ((j >> 10) << 3);
        blk = (g << 10) + (j & 1023);
    }
    int wid  = blk * 4 + (threadIdx.x >> 6);
    int lane = threadIdx.x & 63;
    if (wid >= N) return;
    int beg = rowptr[wid], end = rowptr[wid + 1];
    int grp = lane >> 4;
    int sub = lane & 15;
    float4 acc = {0.f, 0.f, 0.f, 0.f};
    int j = beg + grp;
    for (; j + 12 < end; j += 16) {     // 4 independent chains per group
        int s0 = ssrc[j];
        int s1 = ssrc[j + 4];
        int s2 = ssrc[j + 8];
        int s3 = ssrc[j + 12];
        uint2 u0 = *(const uint2*)(h + (size_t)s0 * 64 + sub * 4);
        uint2 u1 = *(const uint2*)(h + (size_t)s1 * 64 + sub * 4);
        uint2 u2 = *(const uint2*)(h + (size_t)s2 * 64 + sub * 4);
        uint2 u3 = *(const uint2*)(h + (size_t)s3 * 64 + sub * 4);
        acc_h4(acc, u0); acc_h4(acc, u1); acc_h4(acc, u2); acc_h4(acc, u3);
    }
    for (; j < end; j += 4) {
        int s = ssrc[j];
        uint2 u = *(const uint2*)(h + (size_t)s * 64 + sub * 4);
        acc_h4(acc, u);
    }
#pragma unroll
    for (int off = 32; off >= 16; off >>= 1) {
        acc.x += __shfl_down(acc.x, off, 64);
        acc.y += __shfl_down(acc.y, off, 64);
        acc.z += __shfl_down(acc.z, off, 64);
        acc.w += __shfl_down(acc.w, off, 64);
    }
    if (lane < 16) {
        if (fuse_ep) {
            float n = nd[wid];
            const float4 bv = *(const float4*)(b + lane * 4);
            acc.x = acc.x * n + bv.x;
            acc.y = acc.y * n + bv.y;
            acc.z = acc.z * n + bv.z;
            acc.w = acc.w * n + bv.w;
        }
        *(float4*)(out + (size_t)wid * 64 + lane * 4) = acc;
    }
}

// ---------------------------------------------------------------------------
extern "C" void kernel_launch(void* const* d_in, const int* in_sizes, int n_in,
                              void* d_out, int out_size, void* d_ws, size_t ws_size,
                              hipStream_t stream)
{
    const float* x  = (const float*)d_in[0];
    const float* W1 = (const float*)d_in[1];
    const float* b1 = (const float*)d_in[2];
    const float* W2 = (const float*)d_in[3];
    const float* b2 = (const float*)d_in[4];
    const float* W3 = (const float*)d_in[5];
    const float* b3 = (const float*)d_in[6];
    const int*  src = (const int*)d_in[7];
    const int*  dst = (const int*)d_in[8];

    const int E = in_sizes[7];
    const int N = in_sizes[0] / DIM;
    const int epg = E / NG;
    const int npg = N / NG;
    const int chunk = epg / CPG;

    // ws layout: ns[N] | nd[N] | h16[N*64 halves] | rowptr[N+1] | ssrc[E]
    // hsub/dsub (2 MB each) alias h16 (8.4 MB): consumed before gemm1 writes.
    float*  ns     = (float*)d_ws;
    float*  nd     = ns + N;
    __half* h16    = (__half*)(nd + N);
    int*    rowptr = (int*)(h16 + (size_t)N * DIM);
    int*    ssrc   = rowptr + N + 1;
    int*    hsub   = (int*)h16;
    int*    dsub   = hsub + (size_t)NG * CPG * npg;
    float*  agg    = (float*)d_out;

    b1_hist<<<NG * CPG, 256, 0, stream>>>(src, dst, hsub, dsub, chunk, npg);
    b2_scan<<<NG, 1024, 0, stream>>>(hsub, dsub, ns, nd, rowptr, epg, npg, N, E);
    b3_fill<<<NG * CPG, 256, 0, stream>>>(src, dst, dsub, ssrc, chunk, npg);

    const int gemm_blocks = N / 32;
    const int agg_blocks  = N / 4;
    const int swiz = (N == 65536 && npg == 4096) ? 1 : 0;

    gemm_kernel<<<gemm_blocks, 256, 0, stream>>>(x, W1, b1, ns, nd, h16, 0, swiz);
    gather_kernel<<<agg_blocks, 256, 0, stream>>>(h16, ssrc, rowptr, agg, nd, b3, N, 0, swiz);

    gemm_kernel<<<gemm_blocks, 256, 0, stream>>>(agg, W2, b1, ns, nd, h16, 1, swiz);
    gather_kernel<<<agg_blocks, 256, 0, stream>>>(h16, ssrc, rowptr, agg, nd, b3, N, 0, swiz);

    gemm_kernel<<<gemm_blocks, 256, 0, stream>>>(agg, W3, b2, ns, nd, h16, 1, swiz);
    gather_kernel<<<agg_blocks, 256, 0, stream>>>(h16, ssrc, rowptr, agg, nd, b3, N, 1, swiz);
}